// Round 1
// baseline (5522.922 us; speedup 1.0000x reference)
//
#include <hip/hip_runtime.h>
#include <cmath>

#define N_NODES 100000
#define N_EDGES 1600000
#define IN_DIM 128
#define HID 96
#define NCLS 16

// ---------------------------------------------------------------------------
// GEMM: out[r][c] = sum_k (X[r][k] (+ X2[r][k])) * W[k][c] + b[c]
// W (K x 96) staged in LDS. One thread per output element, grid-stride.
// ---------------------------------------------------------------------------
template <int K, bool ADD2>
__global__ void gemm_kernel(const float* __restrict__ X, const float* __restrict__ X2,
                            const float* __restrict__ W, const float* __restrict__ b,
                            float* __restrict__ out, int N) {
    __shared__ float Ws[K * HID];
    __shared__ float bs[HID];
    for (int i = threadIdx.x; i < K * HID; i += blockDim.x) Ws[i] = W[i];
    for (int i = threadIdx.x; i < HID; i += blockDim.x) bs[i] = b[i];
    __syncthreads();

    int total = N * HID;
    for (int idx = blockIdx.x * blockDim.x + threadIdx.x; idx < total;
         idx += gridDim.x * blockDim.x) {
        int r = idx / HID;
        int c = idx - r * HID;
        const float* xr = X + (size_t)r * K;
        const float* x2r = ADD2 ? (X2 + (size_t)r * K) : nullptr;
        float acc = bs[c];
#pragma unroll 8
        for (int k = 0; k < K; ++k) {
            float xv = xr[k];
            if (ADD2) xv += x2r[k];
            acc = fmaf(xv, Ws[k * HID + c], acc);
        }
        out[idx] = acc;
    }
}

// ---------------------------------------------------------------------------
// Edge aggregation: agg[dst[e]] += h[src[e]]  (float4 per thread, atomics)
// ---------------------------------------------------------------------------
__global__ void agg_kernel(const float* __restrict__ H, const int* __restrict__ src,
                           const int* __restrict__ dst, float* __restrict__ agg) {
    const int QPR = HID / 4;  // 24 float4 per row
    int total = N_EDGES * QPR;
    for (int idx = blockIdx.x * blockDim.x + threadIdx.x; idx < total;
         idx += gridDim.x * blockDim.x) {
        int e = idx / QPR;
        int q = idx - e * QPR;
        int s = src[e];
        int d = dst[e];
        float4 v = ((const float4*)(H + (size_t)s * HID))[q];
        float* ap = agg + (size_t)d * HID + q * 4;
        unsafeAtomicAdd(ap + 0, v.x);
        unsafeAtomicAdd(ap + 1, v.y);
        unsafeAtomicAdd(ap + 2, v.z);
        unsafeAtomicAdd(ap + 3, v.w);
    }
}

// ---------------------------------------------------------------------------
// BatchNorm stats: one block per feature column. Double accumulation.
// Emits folded scale = g*rstd, shift = be - mu*g*rstd.
// ---------------------------------------------------------------------------
__global__ void bn_stats_kernel(const float* __restrict__ Z, const float* __restrict__ g,
                                const float* __restrict__ be, float* __restrict__ scale,
                                float* __restrict__ shift) {
    int c = blockIdx.x;  // 0..HID-1
    double sum = 0.0, sumsq = 0.0;
    for (int r = threadIdx.x; r < N_NODES; r += blockDim.x) {
        float v = Z[(size_t)r * HID + c];
        sum += v;
        sumsq += (double)v * v;
    }
    for (int off = 32; off > 0; off >>= 1) {
        sum += __shfl_down(sum, off, 64);
        sumsq += __shfl_down(sumsq, off, 64);
    }
    __shared__ double ssum[8], ssq[8];
    int wave = threadIdx.x >> 6, lane = threadIdx.x & 63;
    if (lane == 0) { ssum[wave] = sum; ssq[wave] = sumsq; }
    __syncthreads();
    if (threadIdx.x == 0) {
        int nw = blockDim.x >> 6;
        double S = 0.0, Q = 0.0;
        for (int w = 0; w < nw; ++w) { S += ssum[w]; Q += ssq[w]; }
        double mu = S / N_NODES;
        double var = Q / N_NODES - mu * mu;
        float rstd = (float)(1.0 / sqrt(var + 1e-5));
        float sc = rstd * g[c];
        scale[c] = sc;
        shift[c] = be[c] - (float)mu * sc;
    }
}

// ---------------------------------------------------------------------------
// BN apply + ReLU, elementwise
// ---------------------------------------------------------------------------
__global__ void bn_relu_kernel(const float* __restrict__ Z, const float* __restrict__ scale,
                               const float* __restrict__ shift, float* __restrict__ out) {
    int total = N_NODES * HID;
    for (int idx = blockIdx.x * blockDim.x + threadIdx.x; idx < total;
         idx += gridDim.x * blockDim.x) {
        int r = idx / HID;
        int c = idx - r * HID;
        float v = fmaf(Z[idx], scale[c], shift[c]);
        out[idx] = v > 0.f ? v : 0.f;
    }
}

// ---------------------------------------------------------------------------
// Readout GEMM (96x16) + log_softmax, one thread per row
// ---------------------------------------------------------------------------
__global__ void readout_kernel(const float* __restrict__ X, const float* __restrict__ Wr,
                               const float* __restrict__ br, float* __restrict__ out) {
    __shared__ float Ws[HID * NCLS];
    __shared__ float bs[NCLS];
    for (int i = threadIdx.x; i < HID * NCLS; i += blockDim.x) Ws[i] = Wr[i];
    if (threadIdx.x < NCLS) bs[threadIdx.x] = br[threadIdx.x];
    __syncthreads();

    for (int r = blockIdx.x * blockDim.x + threadIdx.x; r < N_NODES;
         r += gridDim.x * blockDim.x) {
        float acc[NCLS];
#pragma unroll
        for (int j = 0; j < NCLS; ++j) acc[j] = bs[j];
        const float* xr = X + (size_t)r * HID;
        for (int k = 0; k < HID; ++k) {
            float xv = xr[k];
#pragma unroll
            for (int j = 0; j < NCLS; ++j) acc[j] = fmaf(xv, Ws[k * NCLS + j], acc[j]);
        }
        float m = acc[0];
#pragma unroll
        for (int j = 1; j < NCLS; ++j) m = fmaxf(m, acc[j]);
        float s = 0.f;
#pragma unroll
        for (int j = 0; j < NCLS; ++j) s += expf(acc[j] - m);
        float lse = m + logf(s);
        float* orow = out + (size_t)r * NCLS;
#pragma unroll
        for (int j = 0; j < NCLS; ++j) orow[j] = acc[j] - lse;
    }
}

// ---------------------------------------------------------------------------
extern "C" void kernel_launch(void* const* d_in, const int* in_sizes, int n_in,
                              void* d_out, int out_size, void* d_ws, size_t ws_size,
                              hipStream_t stream) {
    const float* h     = (const float*)d_in[0];
    const int*   src   = (const int*)d_in[1];
    const int*   dst   = (const int*)d_in[2];
    const float* W_emb = (const float*)d_in[3];
    const float* b_emb = (const float*)d_in[4];
    const float* W1    = (const float*)d_in[5];
    const float* b1    = (const float*)d_in[6];
    const float* g1    = (const float*)d_in[7];
    const float* be1   = (const float*)d_in[8];
    const float* W2    = (const float*)d_in[9];
    const float* b2    = (const float*)d_in[10];
    const float* g2    = (const float*)d_in[11];
    const float* be2   = (const float*)d_in[12];
    const float* Wr    = (const float*)d_in[13];
    const float* br    = (const float*)d_in[14];

    const size_t nh = (size_t)N_NODES * HID;
    float* A     = (float*)d_ws;      // current node features
    float* B     = A + nh;            // aggregation buffer
    float* C     = B + nh;            // pre-BN linear output
    float* scale = C + nh;            // HID floats
    float* shift = scale + HID;       // HID floats

    const int threads = 256;
    const int blocksG = (int)((nh + threads - 1) / threads);
    const int blocksA = (N_EDGES * (HID / 4) + threads - 1) / threads;
    const int blocksR = (N_NODES + threads - 1) / threads;

    // 1. embedding: A = h @ W_emb + b_emb
    hipLaunchKernelGGL((gemm_kernel<IN_DIM, false>), dim3(blocksG), dim3(threads), 0, stream,
                       h, nullptr, W_emb, b_emb, A, N_NODES);

    // 2. GIN layer 1
    hipMemsetAsync(B, 0, nh * sizeof(float), stream);
    agg_kernel<<<blocksA, threads, 0, stream>>>(A, src, dst, B);
    hipLaunchKernelGGL((gemm_kernel<HID, true>), dim3(blocksG), dim3(threads), 0, stream,
                       A, B, W1, b1, C, N_NODES);
    bn_stats_kernel<<<HID, 256, 0, stream>>>(C, g1, be1, scale, shift);
    bn_relu_kernel<<<blocksG, threads, 0, stream>>>(C, scale, shift, A);

    // 3. GIN layer 2
    hipMemsetAsync(B, 0, nh * sizeof(float), stream);
    agg_kernel<<<blocksA, threads, 0, stream>>>(A, src, dst, B);
    hipLaunchKernelGGL((gemm_kernel<HID, true>), dim3(blocksG), dim3(threads), 0, stream,
                       A, B, W2, b2, C, N_NODES);
    bn_stats_kernel<<<HID, 256, 0, stream>>>(C, g2, be2, scale, shift);
    bn_relu_kernel<<<blocksG, threads, 0, stream>>>(C, scale, shift, A);

    // 4. readout + log_softmax
    readout_kernel<<<blocksR, threads, 0, stream>>>(A, Wr, br, (float*)d_out);
}

// Round 2
// 674.429 us; speedup vs baseline: 8.1890x; 8.1890x over previous
//
#include <hip/hip_runtime.h>
#include <cmath>

#define N_NODES 100000
#define N_EDGES 1600000
#define IN_DIM 128
#define HID 96
#define NCLS 16
#define NB_SCAN 391  // ceil(N_NODES/256)

// ---------------------------------------------------------------------------
// Register-blocked GEMM: out[r][0..95] = X[r][:] @ W + b
// Each thread: 1 row x 16 cols (6 col-groups). W staged in LDS.
// ---------------------------------------------------------------------------
template <int K>
__global__ __launch_bounds__(256) void gemm_rb(const float* __restrict__ X,
                                               const float* __restrict__ W,
                                               const float* __restrict__ bias,
                                               float* __restrict__ out) {
    __shared__ float Ws[K * HID];
    for (int i = threadIdx.x; i < K * HID; i += 256) Ws[i] = W[i];
    __syncthreads();

    int idx = blockIdx.x * 256 + threadIdx.x;
    int r = idx / 6, g = idx % 6;
    if (r >= N_NODES) return;

    const float* xr = X + (size_t)r * K;
    const float* wcol = Ws + g * 16;
    float acc[16];
#pragma unroll
    for (int j = 0; j < 16; ++j) acc[j] = bias[g * 16 + j];

    for (int k = 0; k < K; k += 4) {
        float4 xv = *(const float4*)(xr + k);
#pragma unroll
        for (int kk = 0; kk < 4; ++kk) {
            float x = kk == 0 ? xv.x : kk == 1 ? xv.y : kk == 2 ? xv.z : xv.w;
            const float* wrow = wcol + (k + kk) * HID;
#pragma unroll
            for (int j = 0; j < 16; j += 4) {
                float4 w = *(const float4*)(wrow + j);
                acc[j + 0] = fmaf(x, w.x, acc[j + 0]);
                acc[j + 1] = fmaf(x, w.y, acc[j + 1]);
                acc[j + 2] = fmaf(x, w.z, acc[j + 2]);
                acc[j + 3] = fmaf(x, w.w, acc[j + 3]);
            }
        }
    }
    float4* orow = (float4*)(out + (size_t)r * HID + g * 16);
#pragma unroll
    for (int j = 0; j < 16; j += 4)
        orow[j / 4] = make_float4(acc[j], acc[j + 1], acc[j + 2], acc[j + 3]);
}

// ---------------------------------------------------------------------------
// CSR build: histogram -> 2-level exclusive scan -> scatter
// ---------------------------------------------------------------------------
__global__ void hist_kernel(const int* __restrict__ dst, int* __restrict__ deg) {
    int e = blockIdx.x * 256 + threadIdx.x;
    if (e < N_EDGES) atomicAdd(&deg[dst[e]], 1);
}

__global__ void scan_blocksum(const int* __restrict__ deg, int* __restrict__ bsums) {
    __shared__ int sm[256];
    int t = threadIdx.x;
    int i = blockIdx.x * 256 + t;
    sm[t] = (i < N_NODES) ? deg[i] : 0;
    __syncthreads();
    for (int s = 128; s > 0; s >>= 1) {
        if (t < s) sm[t] += sm[t + s];
        __syncthreads();
    }
    if (t == 0) bsums[blockIdx.x] = sm[0];
}

__global__ void scan_offsets(const int* __restrict__ bsums, int* __restrict__ boffs) {
    __shared__ int tmp[512];
    int t = threadIdx.x;
    int v = (t < NB_SCAN) ? bsums[t] : 0;
    tmp[t] = v;
    __syncthreads();
    for (int off = 1; off < 512; off <<= 1) {
        int a = (t >= off) ? tmp[t - off] : 0;
        __syncthreads();
        tmp[t] += a;
        __syncthreads();
    }
    if (t < NB_SCAN) boffs[t] = tmp[t] - v;  // exclusive
}

__global__ void scan_final(const int* __restrict__ deg, const int* __restrict__ boffs,
                           int* __restrict__ rp, int* __restrict__ cursor) {
    __shared__ int tmp[256];
    int t = threadIdx.x;
    int i = blockIdx.x * 256 + t;
    int val = (i < N_NODES) ? deg[i] : 0;
    tmp[t] = val;
    __syncthreads();
    for (int off = 1; off < 256; off <<= 1) {
        int a = (t >= off) ? tmp[t - off] : 0;
        __syncthreads();
        tmp[t] += a;
        __syncthreads();
    }
    int excl = tmp[t] - val + boffs[blockIdx.x];
    if (i < N_NODES) {
        rp[i] = excl;
        cursor[i] = excl;
        if (i == N_NODES - 1) rp[N_NODES] = excl + val;
    }
}

__global__ void scatter_kernel(const int* __restrict__ src, const int* __restrict__ dst,
                               int* __restrict__ cursor, int* __restrict__ cols) {
    int e = blockIdx.x * 256 + threadIdx.x;
    if (e < N_EDGES) {
        int d = dst[e];
        int p = atomicAdd(&cursor[d], 1);
        cols[p] = src[e];
    }
}

// ---------------------------------------------------------------------------
// Gather aggregation: out[v] = f(H[v]) + sum_{u in in(v)} f(H[u])
// where f = identity or relu(x*scale+shift) (BN of previous layer, fused).
// 24 threads per node, one float4 column chunk each.
// ---------------------------------------------------------------------------
__device__ __forceinline__ float4 bn_relu4(float4 x, float4 sc, float4 sh) {
    float4 r;
    r.x = fmaxf(fmaf(x.x, sc.x, sh.x), 0.f);
    r.y = fmaxf(fmaf(x.y, sc.y, sh.y), 0.f);
    r.z = fmaxf(fmaf(x.z, sc.z, sh.z), 0.f);
    r.w = fmaxf(fmaf(x.w, sc.w, sh.w), 0.f);
    return r;
}
__device__ __forceinline__ void acc4(float4& a, float4 x) {
    a.x += x.x; a.y += x.y; a.z += x.z; a.w += x.w;
}

template <bool BN>
__global__ __launch_bounds__(192) void gather_kernel(const float* __restrict__ H,
                                                     const int* __restrict__ rp,
                                                     const int* __restrict__ cols,
                                                     const float* __restrict__ scale,
                                                     const float* __restrict__ shift,
                                                     float* __restrict__ out) {
    int idx = blockIdx.x * 192 + threadIdx.x;
    int v = idx / 24, q = idx % 24;
    if (v >= N_NODES) return;

    float4 sc, sh;
    if (BN) {
        sc = ((const float4*)scale)[q];
        sh = ((const float4*)shift)[q];
    }
    const float4* Hq = (const float4*)H;  // row stride = 24 float4

    float4 self = Hq[(size_t)v * 24 + q];
    float4 acc = BN ? bn_relu4(self, sc, sh) : self;

    int beg = rp[v], end = rp[v + 1];
    int j = beg;
    for (; j + 1 < end; j += 2) {
        int u0 = cols[j], u1 = cols[j + 1];
        float4 x0 = Hq[(size_t)u0 * 24 + q];
        float4 x1 = Hq[(size_t)u1 * 24 + q];
        acc4(acc, BN ? bn_relu4(x0, sc, sh) : x0);
        acc4(acc, BN ? bn_relu4(x1, sc, sh) : x1);
    }
    if (j < end) {
        int u = cols[j];
        float4 x = Hq[(size_t)u * 24 + q];
        acc4(acc, BN ? bn_relu4(x, sc, sh) : x);
    }
    ((float4*)out)[(size_t)v * 24 + q] = acc;
}

// ---------------------------------------------------------------------------
// BN stats, coalesced: blockDim=384 (4 rows x 96 cols per iter), LDS reduce,
// float atomics into global sums/sumsq.
// ---------------------------------------------------------------------------
__global__ __launch_bounds__(384) void bn_stats(const float* __restrict__ Z,
                                                float* __restrict__ sums,
                                                float* __restrict__ sumsq) {
    int c = threadIdx.x % 96, rs = threadIdx.x / 96;
    float s = 0.f, q = 0.f;
    for (int r = blockIdx.x * 4 + rs; r < N_NODES; r += gridDim.x * 4) {
        float v = Z[(size_t)r * 96 + c];
        s += v;
        q = fmaf(v, v, q);
    }
    __shared__ float ls[384], lq[384];
    ls[threadIdx.x] = s;
    lq[threadIdx.x] = q;
    __syncthreads();
    if (threadIdx.x < 96) {
        s = ls[threadIdx.x] + ls[96 + threadIdx.x] + ls[192 + threadIdx.x] + ls[288 + threadIdx.x];
        q = lq[threadIdx.x] + lq[96 + threadIdx.x] + lq[192 + threadIdx.x] + lq[288 + threadIdx.x];
        unsafeAtomicAdd(&sums[threadIdx.x], s);
        unsafeAtomicAdd(&sumsq[threadIdx.x], q);
    }
}

__global__ void bn_finalize(const float* __restrict__ sums, const float* __restrict__ sumsq,
                            const float* __restrict__ g, const float* __restrict__ be,
                            float* __restrict__ scale, float* __restrict__ shift) {
    int c = threadIdx.x;
    if (c < HID) {
        float mu = sums[c] * (1.0f / N_NODES);
        float var = sumsq[c] * (1.0f / N_NODES) - mu * mu;
        float rstd = rsqrtf(var + 1e-5f);
        float s = g[c] * rstd;
        scale[c] = s;
        shift[c] = be[c] - mu * s;
    }
}

// ---------------------------------------------------------------------------
// Readout: x = relu(bn2(C2)) on the fly, then @ Wr + br, then log_softmax.
// ---------------------------------------------------------------------------
__global__ __launch_bounds__(256) void readout_kernel(const float* __restrict__ X,
                                                      const float* __restrict__ scale,
                                                      const float* __restrict__ shift,
                                                      const float* __restrict__ Wr,
                                                      const float* __restrict__ br,
                                                      float* __restrict__ out) {
    __shared__ float Ws[HID * NCLS];
    __shared__ float bs[NCLS];
    __shared__ float scs[HID], shs[HID];
    for (int i = threadIdx.x; i < HID * NCLS; i += 256) Ws[i] = Wr[i];
    if (threadIdx.x < NCLS) bs[threadIdx.x] = br[threadIdx.x];
    if (threadIdx.x < HID) {
        scs[threadIdx.x] = scale[threadIdx.x];
        shs[threadIdx.x] = shift[threadIdx.x];
    }
    __syncthreads();

    int r = blockIdx.x * 256 + threadIdx.x;
    if (r >= N_NODES) return;

    float acc[NCLS];
#pragma unroll
    for (int j = 0; j < NCLS; ++j) acc[j] = bs[j];
    const float* xr = X + (size_t)r * HID;
    for (int k = 0; k < HID; ++k) {
        float xv = fmaxf(fmaf(xr[k], scs[k], shs[k]), 0.f);
#pragma unroll
        for (int j = 0; j < NCLS; ++j) acc[j] = fmaf(xv, Ws[k * NCLS + j], acc[j]);
    }
    float m = acc[0];
#pragma unroll
    for (int j = 1; j < NCLS; ++j) m = fmaxf(m, acc[j]);
    float s = 0.f;
#pragma unroll
    for (int j = 0; j < NCLS; ++j) s += expf(acc[j] - m);
    float lse = m + logf(s);
    float* orow = out + (size_t)r * NCLS;
#pragma unroll
    for (int j = 0; j < NCLS; ++j) orow[j] = acc[j] - lse;
}

// ---------------------------------------------------------------------------
extern "C" void kernel_launch(void* const* d_in, const int* in_sizes, int n_in,
                              void* d_out, int out_size, void* d_ws, size_t ws_size,
                              hipStream_t stream) {
    const float* h     = (const float*)d_in[0];
    const int*   src   = (const int*)d_in[1];
    const int*   dst   = (const int*)d_in[2];
    const float* W_emb = (const float*)d_in[3];
    const float* b_emb = (const float*)d_in[4];
    const float* W1    = (const float*)d_in[5];
    const float* b1    = (const float*)d_in[6];
    const float* g1    = (const float*)d_in[7];
    const float* be1   = (const float*)d_in[8];
    const float* W2    = (const float*)d_in[9];
    const float* b2    = (const float*)d_in[10];
    const float* g2    = (const float*)d_in[11];
    const float* be2   = (const float*)d_in[12];
    const float* Wr    = (const float*)d_in[13];
    const float* br    = (const float*)d_in[14];

    const size_t nh = (size_t)N_NODES * HID;
    float* P0 = (float*)d_ws;          // 38.4 MB
    float* P1 = P0 + nh;               // 38.4 MB
    int* deg    = (int*)(P1 + nh);     // N
    int* rp     = deg + N_NODES;       // N+1
    int* cursor = rp + N_NODES + 1;    // N
    int* cols   = cursor + N_NODES;    // E
    int* bsums  = cols + N_EDGES;      // NB_SCAN
    int* boffs  = bsums + 512;         // NB_SCAN
    float* sums  = (float*)(boffs + 512);  // 96
    float* sumsq = sums + 96;              // 96
    float* scale = sumsq + 96;             // 96
    float* shift = scale + 96;             // 96

    const int blkE = (N_EDGES + 255) / 256;          // 6250
    const int blkG = (N_NODES * 6 + 255) / 256;      // 2344
    const int blkA = (N_NODES * 24 + 191) / 192;     // 12500
    const int blkR = (N_NODES + 255) / 256;          // 391

    // --- CSR build (reused by both layers) ---
    hipMemsetAsync(deg, 0, N_NODES * sizeof(int), stream);
    hist_kernel<<<blkE, 256, 0, stream>>>(dst, deg);
    scan_blocksum<<<NB_SCAN, 256, 0, stream>>>(deg, bsums);
    scan_offsets<<<1, 512, 0, stream>>>(bsums, boffs);
    scan_final<<<NB_SCAN, 256, 0, stream>>>(deg, boffs, rp, cursor);
    scatter_kernel<<<blkE, 256, 0, stream>>>(src, dst, cursor, cols);

    // --- embedding: P0 = h @ W_emb + b_emb ---
    hipLaunchKernelGGL((gemm_rb<IN_DIM>), dim3(blkG), dim3(256), 0, stream,
                       h, W_emb, b_emb, P0);

    // --- GIN layer 1 ---
    hipLaunchKernelGGL((gather_kernel<false>), dim3(blkA), dim3(192), 0, stream,
                       P0, rp, cols, nullptr, nullptr, P1);
    hipLaunchKernelGGL((gemm_rb<HID>), dim3(blkG), dim3(256), 0, stream,
                       P1, W1, b1, P0);                      // P0 = C1
    hipMemsetAsync(sums, 0, 2 * HID * sizeof(float), stream);
    bn_stats<<<256, 384, 0, stream>>>(P0, sums, sumsq);
    bn_finalize<<<1, 128, 0, stream>>>(sums, sumsq, g1, be1, scale, shift);

    // --- GIN layer 2 (BN1+ReLU fused into gather) ---
    hipLaunchKernelGGL((gather_kernel<true>), dim3(blkA), dim3(192), 0, stream,
                       P0, rp, cols, scale, shift, P1);
    hipLaunchKernelGGL((gemm_rb<HID>), dim3(blkG), dim3(256), 0, stream,
                       P1, W2, b2, P0);                      // P0 = C2
    hipMemsetAsync(sums, 0, 2 * HID * sizeof(float), stream);
    bn_stats<<<256, 384, 0, stream>>>(P0, sums, sumsq);
    bn_finalize<<<1, 128, 0, stream>>>(sums, sumsq, g2, be2, scale, shift);

    // --- readout (BN2+ReLU fused) + log_softmax ---
    readout_kernel<<<blkR, 256, 0, stream>>>(P0, scale, shift, Wr, br, (float*)d_out);
}